// Round 12
// baseline (1687.162 us; speedup 1.0000x reference)
//
#include <hip/hip_runtime.h>

#define B_ 32
#define P_ 2048
#define K_ 20

// ---- order-preserving (key, idx) packing -------------------------------
__device__ inline unsigned monok(float key) {
  unsigned u = __float_as_uint(key);
  return u ^ (((unsigned)((int)u >> 31)) | 0x80000000u);  // monotone f32->u32
}
__device__ inline float unmonok(unsigned u) {
  return __uint_as_float((u & 0x80000000u) ? (u ^ 0x80000000u) : ~u);
}
__device__ inline unsigned long long pack_key(float key, int j) {
  return ((unsigned long long)monok(key) << 32) | (unsigned)(~j);
}

// Full ascending bitonic sort of 64 u64 across the wave's lanes.
__device__ inline unsigned long long sort64(unsigned long long v, int lane) {
#pragma unroll
  for (int k = 2; k <= 64; k <<= 1) {
#pragma unroll
    for (int j = k >> 1; j > 0; j >>= 1) {
      unsigned long long o = __shfl_xor(v, j, 64);
      bool keepMin = ((lane & j) == 0) == ((lane & k) == 0);
      unsigned long long mn = v < o ? v : o;
      unsigned long long mx = v < o ? o : v;
      v = keepMin ? mn : mx;
    }
  }
  return v;
}

// Seed top-20 list from 64 candidates: sort asc, top-20 -> lanes 0..19.
__device__ inline unsigned long long topk_seed(unsigned long long x, int lane) {
  unsigned long long s = sort64(x, lane);
  unsigned long long v = __shfl(s, lane + 44, 64);
  return (lane < K_) ? v : ~0ULL;
}

// ---- slim wave-distributed top-K drains --------------------------------
template <int STRIDE>
__device__ inline void drain_f(unsigned long long& t, float keyf, int jbase,
                               unsigned& tauU, float& tauf) {
  unsigned long long mask = __ballot(keyf >= tauf);
  while (mask) {
    int src = (int)__builtin_ctzll(mask);
    mask &= mask - 1;
    unsigned kb = (unsigned)__builtin_amdgcn_readlane(__float_as_int(keyf), src);
    unsigned kU = kb ^ (((unsigned)((int)kb >> 31)) | 0x80000000u);
    if (kU < tauU) continue;  // stale (scalar cmp+branch)
    unsigned long long xi =
        ((unsigned long long)kU << 32) | (unsigned)(~(jbase + src * STRIDE));
    unsigned long long up = __shfl_down(t, 1, 64);
    bool c1 = t < xi;
    bool c2 = up < xi;
    unsigned long long v = c1 ? xi : t;
    t = c2 ? up : v;
    tauU = (unsigned)__builtin_amdgcn_readlane((int)(unsigned)(t >> 32), 0);
    tauf = unmonok(tauU);
  }
}
template <int STRIDE>
__device__ inline void drain_u(unsigned long long& t, unsigned keyU, int jbase,
                               unsigned& tauU) {
  unsigned long long mask = __ballot(keyU >= tauU);
  while (mask) {
    int src = (int)__builtin_ctzll(mask);
    mask &= mask - 1;
    unsigned kU = (unsigned)__builtin_amdgcn_readlane((int)keyU, src);
    if (kU < tauU) continue;
    unsigned long long xi =
        ((unsigned long long)kU << 32) | (unsigned)(~(jbase + src * STRIDE));
    unsigned long long up = __shfl_down(t, 1, 64);
    bool c1 = t < xi;
    bool c2 = up < xi;
    unsigned long long v = c1 ? xi : t;
    t = c2 ? up : v;
    tauU = (unsigned)__builtin_amdgcn_readlane((int)(unsigned)(t >> 32), 0);
  }
}

// ---------------- Kernel 0: pts4[i] = (x, y, z, x^2+y^2+z^2) ------------
__global__ __launch_bounds__(256) void pts4_kernel(
    const float* __restrict__ pos, float4* __restrict__ pts4) {
  int i = blockIdx.x * 256 + threadIdx.x;  // over B*P
  const float* p = pos + (size_t)i * 3;
  float x = p[0], y = p[1], z = p[2];
  pts4[i] = make_float4(x, y, z, x * x + y * y + z * z);
}

// ---------------- Kernel 1: kNN on 3-D positions -> idx1 ----------------
__global__ __launch_bounds__(256) void knn3_kernel(
    const float4* __restrict__ pts4, int* __restrict__ idx) {
  int b = blockIdx.y;
  const float4* pb = pts4 + (size_t)b * P_;
  int wv = threadIdx.x >> 6;
  int lane = threadIdx.x & 63;
  int row0 = blockIdx.x * 16 + wv * 4;
  float4 pi[4];
#pragma unroll
  for (int rr = 0; rr < 4; ++rr) {
    float4 p = pb[row0 + rr];  // broadcast load
    pi[rr] = make_float4(2.f * p.x, 2.f * p.y, 2.f * p.z, p.w);
  }
  unsigned long long t[4];
  unsigned tauU[4];
  float tauf[4];
  {
    float4 pj = pb[lane];
#pragma unroll
    for (int rr = 0; rr < 4; ++rr) {
      float key = fmaf(pi[rr].x, pj.x,
                  fmaf(pi[rr].y, pj.y, fmaf(pi[rr].z, pj.z, -pj.w)));
      t[rr] = topk_seed(pack_key(key, lane), lane);
      tauU[rr] = (unsigned)__builtin_amdgcn_readlane(
          (int)(unsigned)(t[rr] >> 32), 0);
      tauf[rr] = unmonok(tauU[rr]);
    }
  }
#pragma unroll 1
  for (int ch = 1; ch < 32; ++ch) {
    float4 pj = pb[ch * 64 + lane];  // coalesced global (L2)
#pragma unroll
    for (int rr = 0; rr < 4; ++rr) {
      float key = fmaf(pi[rr].x, pj.x,
                  fmaf(pi[rr].y, pj.y, fmaf(pi[rr].z, pj.z, -pj.w)));
      drain_f<1>(t[rr], key, ch * 64, tauU[rr], tauf[rr]);
    }
  }
  if (lane < K_) {
#pragma unroll
    for (int rr = 0; rr < 4; ++rr)
      idx[((size_t)b * P_ + row0 + rr) * K_ + lane] = (int)(~(unsigned)t[rr]);
  }
}

// ---------------- Kernel 3: layer-1 edge MLP + max over K -> x1, d2 -----
__global__ __launch_bounds__(256) void layer1_kernel(
    const float* __restrict__ pos, const float* __restrict__ W1,
    const float* __restrict__ b1, const float* __restrict__ g1,
    const float* __restrict__ bt1, const float* __restrict__ W2,
    const float* __restrict__ b2, const int* __restrict__ idx,
    float* __restrict__ x1, float* __restrict__ d2out) {
  __shared__ __align__(16) float W2t[64 * 68];  // W2t[n][c] = W2[c][n]
  __shared__ __align__(16) float A[80 * 68];    // T rows: p*20+k
  __shared__ float pmax[4][4][64];
  int b = blockIdx.y;
  int tid = threadIdx.x;
  int lane = tid & 63;
  int w = tid >> 6;
  for (int t = tid; t < 64 * 64; t += 256) {
    int c = t >> 6, n = t & 63;
    W2t[n * 68 + c] = W2[c * 64 + n];
  }
  int i = blockIdx.x * 4 + w;
  size_t ip = (size_t)b * P_ + i;
  const float* posi = pos + ip * 3;
  float px = posi[0], py = posi[1], pz = posi[2];
  int c = lane;
  float w3 = W1[3 * 64 + c], w4 = W1[4 * 64 + c], w5 = W1[5 * 64 + c];
  float cv = px * (W1[0 * 64 + c] - w3) + py * (W1[1 * 64 + c] - w4) +
             pz * (W1[2 * 64 + c] - w5) + b1[c];
  float g = g1[c], bt = bt1[c];
  const int* ji = idx + ip * K_;
  const float* posb = pos + (size_t)b * P_ * 3;
  for (int k = 0; k < K_; ++k) {
    int j = ji[k];  // broadcast
    const float* pj = posb + (size_t)j * 3;
    float xj = pj[0], yj = pj[1], zj = pj[2];
    float t = cv + fmaf(xj, w3, fmaf(yj, w4, zj * w5));
    t = fmaxf(fmaf(t, g, bt), 0.f);
    A[(w * K_ + k) * 68 + c] = t;
  }
  __syncthreads();

  int tr = tid >> 4;  // rows tr*5..tr*5+4
  int tc = tid & 15;  // cols tc + 16*cc
  float acc[5][4];
#pragma unroll
  for (int a = 0; a < 5; ++a)
#pragma unroll
    for (int cc = 0; cc < 4; ++cc) acc[a][cc] = 0.f;
#pragma unroll
  for (int c4 = 0; c4 < 16; ++c4) {
    float4 af[5], bf[4];
#pragma unroll
    for (int a = 0; a < 5; ++a)
      af[a] = *(const float4*)(&A[(tr * 5 + a) * 68 + c4 * 4]);
#pragma unroll
    for (int cc = 0; cc < 4; ++cc)
      bf[cc] = *(const float4*)(&W2t[(tc + 16 * cc) * 68 + c4 * 4]);
#pragma unroll
    for (int a = 0; a < 5; ++a)
#pragma unroll
      for (int cc = 0; cc < 4; ++cc) {
        float s = acc[a][cc];
        s = fmaf(af[a].x, bf[cc].x, s);
        s = fmaf(af[a].y, bf[cc].y, s);
        s = fmaf(af[a].z, bf[cc].z, s);
        s = fmaf(af[a].w, bf[cc].w, s);
        acc[a][cc] = s;
      }
  }
#pragma unroll
  for (int cc = 0; cc < 4; ++cc) {
    float m = acc[0][cc];
#pragma unroll
    for (int a = 1; a < 5; ++a) m = fmaxf(m, acc[a][cc]);
    pmax[tr >> 2][tr & 3][tc + 16 * cc] = m;
  }
  __syncthreads();
  {
    int p = tid >> 6, col = tid & 63;
    float m = fmaxf(fmaxf(pmax[p][0][col], pmax[p][1][col]),
                    fmaxf(pmax[p][2][col], pmax[p][3][col]));
    m += b2[col];
    size_t ipp = (size_t)b * P_ + blockIdx.x * 4 + p;
    x1[ipp * 64 + col] = m;
    float s = m * m;
#pragma unroll
    for (int off = 32; off; off >>= 1) s += __shfl_xor(s, off, 64);
    if (col == 0) d2out[ipp] = s;
  }
}

// ---------------- Kernel 4: fused Gram GEMM + top-20 select -> idx2 -----
// grid (P/128, B), block 256 (4 waves). Per block: 128 rows, loop 16
// col-tiles of 128. GEMM 8x8 microtile -> monok keys in Cs (dword stride
// 129: store banks = (lane+const)%32 -> 2-way = free). Select: wave owns
// 32 rows, 2 ballot-chunks of 64 per row, slim drain + tile-0 sort-seed.
// No global scores buffer: kills 512MB write + 512MB read + 15 launches.
__global__ __launch_bounds__(256) void knn2_fused_kernel(
    const float* __restrict__ x1, const float* __restrict__ d2g,
    int* __restrict__ idx) {
  __shared__ __align__(16) float As[128 * 68];   // 34,816 B
  __shared__ __align__(16) float Bs[128 * 68];   // 34,816 B
  __shared__ unsigned Cs[128 * 129];             // 66,048 B
  __shared__ float d2s[128];
  int b = blockIdx.y;
  int r0 = blockIdx.x * 128;
  const float* xb = x1 + (size_t)b * P_ * 64;
  int tid = threadIdx.x;
  int tr = tid >> 4;  // 0..15 -> rows tr*8+a
  int tc = tid & 15;  // cols tc+16*c
  int wv = tid >> 6;  // select rows wv*32..+31
  int lane = tid & 63;

  for (int g = tid; g < 128 * 16; g += 256) {
    int r = g >> 4, c4 = g & 15;
    *(float4*)&As[r * 68 + c4 * 4] =
        *(const float4*)(xb + (size_t)(r0 + r) * 64 + c4 * 4);
  }

  unsigned long long t[32];
  unsigned tauU[32];

#pragma unroll 1
  for (int tile = 0; tile < 16; ++tile) {
    int j0 = tile * 128;
    __syncthreads();  // select(tile-1) done; Bs/Cs free (covers As for t0)
    for (int g = tid; g < 128 * 16; g += 256) {
      int r = g >> 4, c4 = g & 15;
      *(float4*)&Bs[r * 68 + c4 * 4] =
          *(const float4*)(xb + (size_t)(j0 + r) * 64 + c4 * 4);
    }
    if (tid < 128) d2s[tid] = d2g[(size_t)b * P_ + j0 + tid];
    __syncthreads();

    float acc[8][8];
#pragma unroll
    for (int a = 0; a < 8; ++a)
#pragma unroll
      for (int c = 0; c < 8; ++c) acc[a][c] = 0.f;
#pragma unroll
    for (int c4 = 0; c4 < 16; ++c4) {
      float4 af[8], bf[8];
#pragma unroll
      for (int a = 0; a < 8; ++a)
        af[a] = *(const float4*)(&As[(tr * 8 + a) * 68 + c4 * 4]);
#pragma unroll
      for (int c = 0; c < 8; ++c)
        bf[c] = *(const float4*)(&Bs[(tc + 16 * c) * 68 + c4 * 4]);
#pragma unroll
      for (int a = 0; a < 8; ++a)
#pragma unroll
        for (int c = 0; c < 8; ++c) {
          float s = acc[a][c];
          s = fmaf(af[a].x, bf[c].x, s);
          s = fmaf(af[a].y, bf[c].y, s);
          s = fmaf(af[a].z, bf[c].z, s);
          s = fmaf(af[a].w, bf[c].w, s);
          acc[a][c] = s;
        }
    }
#pragma unroll
    for (int a = 0; a < 8; ++a)
#pragma unroll
      for (int c = 0; c < 8; ++c) {
        int col = tc + 16 * c;
        Cs[(tr * 8 + a) * 129 + col] = monok(2.f * acc[a][c] - d2s[col]);
      }
    __syncthreads();  // Cs ready

    if (tile == 0) {
#pragma unroll
      for (int rr = 0; rr < 32; ++rr) {
        int row = wv * 32 + rr;
        unsigned k0 = Cs[row * 129 + lane];
        t[rr] = topk_seed(((unsigned long long)k0 << 32) | (unsigned)(~lane),
                          lane);
        tauU[rr] = (unsigned)__builtin_amdgcn_readlane(
            (int)(unsigned)(t[rr] >> 32), 0);
        unsigned k1 = Cs[row * 129 + 64 + lane];
        drain_u<1>(t[rr], k1, 64, tauU[rr]);
      }
    } else {
#pragma unroll
      for (int rr = 0; rr < 32; ++rr) {
        int row = wv * 32 + rr;
        unsigned k0 = Cs[row * 129 + lane];
        drain_u<1>(t[rr], k0, j0, tauU[rr]);
        unsigned k1 = Cs[row * 129 + 64 + lane];
        drain_u<1>(t[rr], k1, j0 + 64, tauU[rr]);
      }
    }
  }

  if (lane < K_) {
#pragma unroll
    for (int rr = 0; rr < 32; ++rr) {
      int row = wv * 32 + rr;
      idx[((size_t)b * P_ + r0 + row) * K_ + lane] = (int)(~(unsigned)t[rr]);
    }
  }
}

// ---------------- Kernel 5: e2 = x1@(W3a-W3b)+b3, bb2 = x1@W3b ----------
__global__ __launch_bounds__(256) void ebb_kernel(
    const float* __restrict__ x1, const float* __restrict__ W3,
    const float* __restrict__ b3, float* __restrict__ e2,
    float* __restrict__ bb2) {
  __shared__ float xs[16 * 64];
  size_t p0 = (size_t)blockIdx.x * 16;
  for (int v = threadIdx.x; v < 16 * 64; v += 256) xs[v] = x1[p0 * 64 + v];
  __syncthreads();
  int n = threadIdx.x & 127;
  int which = threadIdx.x >> 7;  // wave-uniform
  float acc[16];
#pragma unroll
  for (int p = 0; p < 16; ++p) acc[p] = 0.f;
  for (int c = 0; c < 64; ++c) {
    float wa = W3[c * 128 + n];
    float wb = W3[(64 + c) * 128 + n];
    float wv = which ? wb : (wa - wb);
#pragma unroll
    for (int p = 0; p < 16; ++p) acc[p] += xs[p * 64 + c] * wv;
  }
  float bias = which ? 0.f : b3[n];
  float* dst = which ? bb2 : e2;
#pragma unroll
  for (int p = 0; p < 16; ++p) dst[(p0 + p) * 128 + n] = acc[p] + bias;
}

// ---------------- Kernel 6: x2 gather-max + hp@Wl + per-tile max --------
__global__ __launch_bounds__(256) void final_kernel(
    const float* __restrict__ x1, const float* __restrict__ e2,
    const float* __restrict__ bb2, const int* __restrict__ idx,
    const float* __restrict__ Wl, const float* __restrict__ bl,
    float* __restrict__ partial) {
  __shared__ float hp[32][192];
  __shared__ float smax[2][128];
  int b = blockIdx.y;
  int i0 = blockIdx.x * 32;
  size_t gp0 = (size_t)b * P_ + i0;
  for (int v = threadIdx.x; v < 32 * 64; v += 256) {
    int p = v >> 6, c = v & 63;
    hp[p][c] = x1[(gp0 + p) * 64 + c];
  }
  for (int v = threadIdx.x; v < 32 * 128; v += 256) {
    int p = v >> 7, n = v & 127;
    size_t gp = gp0 + p;
    const int* ji = idx + gp * K_;
    float m = -INFINITY;
    for (int k = 0; k < K_; ++k) {
      int j = ji[k];
      m = fmaxf(m, bb2[((size_t)b * P_ + j) * 128 + n]);
    }
    hp[p][64 + n] = e2[gp * 128 + n] + m;
  }
  __syncthreads();
  int n = threadIdx.x & 127;
  int pg = threadIdx.x >> 7;
  float acc[16];
#pragma unroll
  for (int p = 0; p < 16; ++p) acc[p] = 0.f;
  for (int c = 0; c < 192; ++c) {
    float wv = Wl[c * 128 + n];
#pragma unroll
    for (int p = 0; p < 16; ++p) acc[p] += hp[pg * 16 + p][c] * wv;
  }
  float m = -INFINITY;
#pragma unroll
  for (int p = 0; p < 16; ++p) m = fmaxf(m, acc[p]);
  smax[pg][n] = m;
  __syncthreads();
  if (threadIdx.x < 128) {
    float v = fmaxf(smax[0][n], smax[1][n]) + bl[n];
    partial[((size_t)b * 64 + blockIdx.x) * 128 + n] = v;
  }
}

// ---------------- Kernel 7: reduce partial maxes -> out (B,128) ---------
__global__ __launch_bounds__(256) void reduce_kernel(
    const float* __restrict__ partial, float* __restrict__ out) {
  int t = blockIdx.x * 256 + threadIdx.x;  // 4096
  int b = t >> 7, n = t & 127;
  float m = -INFINITY;
  for (int tb = 0; tb < 64; ++tb)
    m = fmaxf(m, partial[((size_t)b * 64 + tb) * 128 + n]);
  out[t] = m;
}

extern "C" void kernel_launch(void* const* d_in, const int* in_sizes, int n_in,
                              void* d_out, int out_size, void* d_ws,
                              size_t ws_size, hipStream_t stream) {
  (void)in_sizes; (void)n_in; (void)out_size; (void)ws_size;
  const float* pos = (const float*)d_in[0];
  const float* W1  = (const float*)d_in[1];
  const float* b1  = (const float*)d_in[2];
  const float* g1  = (const float*)d_in[3];
  const float* bt1 = (const float*)d_in[4];
  const float* W2  = (const float*)d_in[5];
  const float* b2  = (const float*)d_in[6];
  const float* W3  = (const float*)d_in[7];
  const float* b3  = (const float*)d_in[8];
  const float* Wl  = (const float*)d_in[9];
  const float* bl  = (const float*)d_in[10];
  float* out = (float*)d_out;

  // Workspace layout (bytes), peak 90,439,680 (fits prior request):
  //   [0, 5242880)          idx (idx1 then idx2)
  //   [5242880, 22020096)   x1
  //   [22020096, 22282240)  d2
  //   [22282240, 23330816)  partial
  //   [23330816, 90439680)  region: pts4 (knn3) -> e2|bb2 (post-kNN2)
  char* w = (char*)d_ws;
  int*    idxp  = (int*)(w + 0);
  float*  x1p   = (float*)(w + 5242880);
  float*  d2p   = (float*)(w + 22020096);
  float*  partp = (float*)(w + 22282240);
  float4* pts4p = (float4*)(w + 23330816);
  float*  e2p   = (float*)(w + 23330816);
  float*  bb2p  = (float*)(w + 23330816 + 33554432);

  pts4_kernel<<<dim3(B_ * P_ / 256), 256, 0, stream>>>(pos, pts4p);
  knn3_kernel<<<dim3(P_ / 16, B_), 256, 0, stream>>>(pts4p, idxp);
  layer1_kernel<<<dim3(P_ / 4, B_), 256, 0, stream>>>(
      pos, W1, b1, g1, bt1, W2, b2, idxp, x1p, d2p);
  knn2_fused_kernel<<<dim3(P_ / 128, B_), 256, 0, stream>>>(x1p, d2p, idxp);
  ebb_kernel<<<dim3(B_ * P_ / 16), 256, 0, stream>>>(x1p, W3, b3, e2p, bb2p);
  final_kernel<<<dim3(P_ / 32, B_), 256, 0, stream>>>(
      x1p, e2p, bb2p, idxp, Wl, bl, partp);
  reduce_kernel<<<dim3(16), 256, 0, stream>>>(partp, out);
}

// Round 13
// 994.617 us; speedup vs baseline: 1.6963x; 1.6963x over previous
//
#include <hip/hip_runtime.h>

#define B_ 32
#define P_ 2048
#define K_ 20

// ---- order-preserving (key, idx) packing -------------------------------
__device__ inline unsigned monok(float key) {
  unsigned u = __float_as_uint(key);
  return u ^ (((unsigned)((int)u >> 31)) | 0x80000000u);  // monotone f32->u32
}
__device__ inline float unmonok(unsigned u) {
  return __uint_as_float((u & 0x80000000u) ? (u ^ 0x80000000u) : ~u);
}
__device__ inline unsigned long long pack_key(float key, int j) {
  return ((unsigned long long)monok(key) << 32) | (unsigned)(~j);
}

// Full ascending bitonic sort of 64 u64 across the wave's lanes.
__device__ inline unsigned long long sort64(unsigned long long v, int lane) {
#pragma unroll
  for (int k = 2; k <= 64; k <<= 1) {
#pragma unroll
    for (int j = k >> 1; j > 0; j >>= 1) {
      unsigned long long o = __shfl_xor(v, j, 64);
      bool keepMin = ((lane & j) == 0) == ((lane & k) == 0);
      unsigned long long mn = v < o ? v : o;
      unsigned long long mx = v < o ? o : v;
      v = keepMin ? mn : mx;
    }
  }
  return v;
}

// Seed top-20 list from 64 candidates: sort asc, top-20 -> lanes 0..19.
__device__ inline unsigned long long topk_seed(unsigned long long x, int lane) {
  unsigned long long s = sort64(x, lane);
  unsigned long long v = __shfl(s, lane + 44, 64);
  return (lane < K_) ? v : ~0ULL;
}

// ---- slim wave-distributed top-K drains --------------------------------
template <int STRIDE>
__device__ inline void drain_f(unsigned long long& t, float keyf, int jbase,
                               unsigned& tauU, float& tauf) {
  unsigned long long mask = __ballot(keyf >= tauf);
  while (mask) {
    int src = (int)__builtin_ctzll(mask);
    mask &= mask - 1;
    unsigned kb = (unsigned)__builtin_amdgcn_readlane(__float_as_int(keyf), src);
    unsigned kU = kb ^ (((unsigned)((int)kb >> 31)) | 0x80000000u);
    if (kU < tauU) continue;  // stale (scalar cmp+branch)
    unsigned long long xi =
        ((unsigned long long)kU << 32) | (unsigned)(~(jbase + src * STRIDE));
    unsigned long long up = __shfl_down(t, 1, 64);
    bool c1 = t < xi;
    bool c2 = up < xi;
    unsigned long long v = c1 ? xi : t;
    t = c2 ? up : v;
    tauU = (unsigned)__builtin_amdgcn_readlane((int)(unsigned)(t >> 32), 0);
    tauf = unmonok(tauU);
  }
}
template <int STRIDE>
__device__ inline void drain_u(unsigned long long& t, unsigned keyU, int jbase,
                               unsigned& tauU) {
  unsigned long long mask = __ballot(keyU >= tauU);
  while (mask) {
    int src = (int)__builtin_ctzll(mask);
    mask &= mask - 1;
    unsigned kU = (unsigned)__builtin_amdgcn_readlane((int)keyU, src);
    if (kU < tauU) continue;
    unsigned long long xi =
        ((unsigned long long)kU << 32) | (unsigned)(~(jbase + src * STRIDE));
    unsigned long long up = __shfl_down(t, 1, 64);
    bool c1 = t < xi;
    bool c2 = up < xi;
    unsigned long long v = c1 ? xi : t;
    t = c2 ? up : v;
    tauU = (unsigned)__builtin_amdgcn_readlane((int)(unsigned)(t >> 32), 0);
  }
}

// ---------------- Kernel 0: pts4[i] = (x, y, z, x^2+y^2+z^2) ------------
__global__ __launch_bounds__(256) void pts4_kernel(
    const float* __restrict__ pos, float4* __restrict__ pts4) {
  int i = blockIdx.x * 256 + threadIdx.x;  // over B*P
  const float* p = pos + (size_t)i * 3;
  float x = p[0], y = p[1], z = p[2];
  pts4[i] = make_float4(x, y, z, x * x + y * y + z * z);
}

// ---------------- Kernel 1: kNN on 3-D positions -> idx1 ----------------
// LDS-free, 8 rows/wave (per-chunk pj load + loop overhead amortized 2x
// vs round 11's 4 rows). grid (P/32, B), block 256 (4 waves).
__global__ __launch_bounds__(256) void knn3_kernel(
    const float4* __restrict__ pts4, int* __restrict__ idx) {
  int b = blockIdx.y;
  const float4* pb = pts4 + (size_t)b * P_;
  int wv = threadIdx.x >> 6;
  int lane = threadIdx.x & 63;
  int row0 = blockIdx.x * 32 + wv * 8;
  float4 pi[8];
#pragma unroll
  for (int rr = 0; rr < 8; ++rr) {
    float4 p = pb[row0 + rr];  // broadcast load
    pi[rr] = make_float4(2.f * p.x, 2.f * p.y, 2.f * p.z, p.w);
  }
  unsigned long long t[8];
  unsigned tauU[8];
  float tauf[8];
  {
    float4 pj = pb[lane];
#pragma unroll
    for (int rr = 0; rr < 8; ++rr) {
      float key = fmaf(pi[rr].x, pj.x,
                  fmaf(pi[rr].y, pj.y, fmaf(pi[rr].z, pj.z, -pj.w)));
      t[rr] = topk_seed(pack_key(key, lane), lane);
      tauU[rr] = (unsigned)__builtin_amdgcn_readlane(
          (int)(unsigned)(t[rr] >> 32), 0);
      tauf[rr] = unmonok(tauU[rr]);
    }
  }
#pragma unroll 1
  for (int ch = 1; ch < 32; ++ch) {
    float4 pj = pb[ch * 64 + lane];  // coalesced global (L2)
#pragma unroll
    for (int rr = 0; rr < 8; ++rr) {
      float key = fmaf(pi[rr].x, pj.x,
                  fmaf(pi[rr].y, pj.y, fmaf(pi[rr].z, pj.z, -pj.w)));
      drain_f<1>(t[rr], key, ch * 64, tauU[rr], tauf[rr]);
    }
  }
  if (lane < K_) {
#pragma unroll
    for (int rr = 0; rr < 8; ++rr)
      idx[((size_t)b * P_ + row0 + rr) * K_ + lane] = (int)(~(unsigned)t[rr]);
  }
}

// ---------------- Kernel 3: layer-1 edge MLP + max over K -> x1, d2 -----
__global__ __launch_bounds__(256) void layer1_kernel(
    const float* __restrict__ pos, const float* __restrict__ W1,
    const float* __restrict__ b1, const float* __restrict__ g1,
    const float* __restrict__ bt1, const float* __restrict__ W2,
    const float* __restrict__ b2, const int* __restrict__ idx,
    float* __restrict__ x1, float* __restrict__ d2out) {
  __shared__ __align__(16) float W2t[64 * 68];  // W2t[n][c] = W2[c][n]
  __shared__ __align__(16) float A[80 * 68];    // T rows: p*20+k
  __shared__ float pmax[4][4][64];
  int b = blockIdx.y;
  int tid = threadIdx.x;
  int lane = tid & 63;
  int w = tid >> 6;
  for (int t = tid; t < 64 * 64; t += 256) {
    int c = t >> 6, n = t & 63;
    W2t[n * 68 + c] = W2[c * 64 + n];
  }
  int i = blockIdx.x * 4 + w;
  size_t ip = (size_t)b * P_ + i;
  const float* posi = pos + ip * 3;
  float px = posi[0], py = posi[1], pz = posi[2];
  int c = lane;
  float w3 = W1[3 * 64 + c], w4 = W1[4 * 64 + c], w5 = W1[5 * 64 + c];
  float cv = px * (W1[0 * 64 + c] - w3) + py * (W1[1 * 64 + c] - w4) +
             pz * (W1[2 * 64 + c] - w5) + b1[c];
  float g = g1[c], bt = bt1[c];
  const int* ji = idx + ip * K_;
  const float* posb = pos + (size_t)b * P_ * 3;
  for (int k = 0; k < K_; ++k) {
    int j = ji[k];  // broadcast
    const float* pj = posb + (size_t)j * 3;
    float xj = pj[0], yj = pj[1], zj = pj[2];
    float t = cv + fmaf(xj, w3, fmaf(yj, w4, zj * w5));
    t = fmaxf(fmaf(t, g, bt), 0.f);
    A[(w * K_ + k) * 68 + c] = t;
  }
  __syncthreads();

  int tr = tid >> 4;  // rows tr*5..tr*5+4
  int tc = tid & 15;  // cols tc + 16*cc
  float acc[5][4];
#pragma unroll
  for (int a = 0; a < 5; ++a)
#pragma unroll
    for (int cc = 0; cc < 4; ++cc) acc[a][cc] = 0.f;
#pragma unroll
  for (int c4 = 0; c4 < 16; ++c4) {
    float4 af[5], bf[4];
#pragma unroll
    for (int a = 0; a < 5; ++a)
      af[a] = *(const float4*)(&A[(tr * 5 + a) * 68 + c4 * 4]);
#pragma unroll
    for (int cc = 0; cc < 4; ++cc)
      bf[cc] = *(const float4*)(&W2t[(tc + 16 * cc) * 68 + c4 * 4]);
#pragma unroll
    for (int a = 0; a < 5; ++a)
#pragma unroll
      for (int cc = 0; cc < 4; ++cc) {
        float s = acc[a][cc];
        s = fmaf(af[a].x, bf[cc].x, s);
        s = fmaf(af[a].y, bf[cc].y, s);
        s = fmaf(af[a].z, bf[cc].z, s);
        s = fmaf(af[a].w, bf[cc].w, s);
        acc[a][cc] = s;
      }
  }
#pragma unroll
  for (int cc = 0; cc < 4; ++cc) {
    float m = acc[0][cc];
#pragma unroll
    for (int a = 1; a < 5; ++a) m = fmaxf(m, acc[a][cc]);
    pmax[tr >> 2][tr & 3][tc + 16 * cc] = m;
  }
  __syncthreads();
  {
    int p = tid >> 6, col = tid & 63;
    float m = fmaxf(fmaxf(pmax[p][0][col], pmax[p][1][col]),
                    fmaxf(pmax[p][2][col], pmax[p][3][col]));
    m += b2[col];
    size_t ipp = (size_t)b * P_ + blockIdx.x * 4 + p;
    x1[ipp * 64 + col] = m;
    float s = m * m;
#pragma unroll
    for (int off = 32; off; off >>= 1) s += __shfl_xor(s, off, 64);
    if (col == 0) d2out[ipp] = s;
  }
}

// ---------------- Kernel 4a: Gram scores -> packed u32 keys (global) ----
// grid (P/128, P/128, chunkB), block 256. 128x128 tile, K=64 staged once,
// 8x8 microtile.
__global__ __launch_bounds__(256) void gemm_scores_kernel(
    const float* __restrict__ x1, const float* __restrict__ d2g,
    unsigned* __restrict__ scores, int chunkBase) {
  __shared__ __align__(16) float As[128 * 68];   // 34,816 B
  __shared__ __align__(16) float Bs[128 * 68];   // 34,816 B
  __shared__ float d2s[128];
  int bz = blockIdx.z;
  int b = chunkBase + bz;
  int r0 = blockIdx.x * 128;
  int c0 = blockIdx.y * 128;
  const float* xb = x1 + (size_t)b * P_ * 64;
  unsigned* sb = scores + ((size_t)bz * P_ + r0) * P_;
  int tid = threadIdx.x;
  int tr = tid >> 4;  // 0..15 -> rows tr*8+a
  int tc = tid & 15;  // cols tc+16*c

  for (int g = tid; g < 128 * 16; g += 256) {
    int r = g >> 4, c4 = g & 15;
    *(float4*)&As[r * 68 + c4 * 4] =
        *(const float4*)(xb + (size_t)(r0 + r) * 64 + c4 * 4);
  }
  for (int g = tid; g < 128 * 16; g += 256) {
    int r = g >> 4, c4 = g & 15;
    *(float4*)&Bs[r * 68 + c4 * 4] =
        *(const float4*)(xb + (size_t)(c0 + r) * 64 + c4 * 4);
  }
  if (tid < 128) d2s[tid] = d2g[(size_t)b * P_ + c0 + tid];
  __syncthreads();

  float acc[8][8];
#pragma unroll
  for (int a = 0; a < 8; ++a)
#pragma unroll
    for (int c = 0; c < 8; ++c) acc[a][c] = 0.f;
#pragma unroll
  for (int c4 = 0; c4 < 16; ++c4) {
    float4 af[8], bf[8];
#pragma unroll
    for (int a = 0; a < 8; ++a)
      af[a] = *(const float4*)(&As[(tr * 8 + a) * 68 + c4 * 4]);  // broadcast
#pragma unroll
    for (int c = 0; c < 8; ++c)
      bf[c] = *(const float4*)(&Bs[(tc + 16 * c) * 68 + c4 * 4]);  // 2-way
#pragma unroll
    for (int a = 0; a < 8; ++a)
#pragma unroll
      for (int c = 0; c < 8; ++c) {
        float s = acc[a][c];
        s = fmaf(af[a].x, bf[c].x, s);
        s = fmaf(af[a].y, bf[c].y, s);
        s = fmaf(af[a].z, bf[c].z, s);
        s = fmaf(af[a].w, bf[c].w, s);
        acc[a][c] = s;
      }
  }
#pragma unroll
  for (int a = 0; a < 8; ++a)
#pragma unroll
    for (int c = 0; c < 8; ++c) {
      int col = tc + 16 * c;
      sb[(size_t)(tr * 8 + a) * P_ + c0 + col] =
          monok(2.f * acc[a][c] - d2s[col]);
    }
}

// ---------------- Kernel 4b: select top-20 per row from key buffer ------
// grid (P/4, chunkB), block 256: one wave per row, no LDS.
__global__ __launch_bounds__(256) void knn_select_kernel(
    const unsigned* __restrict__ scores, int* __restrict__ idx,
    int chunkBase) {
  int bb = blockIdx.y;
  int b = chunkBase + bb;
  int row = blockIdx.x * 4 + (threadIdx.x >> 6);
  int lane = threadIdx.x & 63;
  const unsigned* sp = scores + ((size_t)bb * P_ + row) * P_;
  unsigned long long t;
  unsigned tauU;
  // it = 0: seed from first stripe (q==0), drain q=1..3
  {
    uint4 kv = *(const uint4*)(sp + lane * 4);
    t = topk_seed(((unsigned long long)kv.x << 32) | (unsigned)(~(lane * 4)),
                  lane);
    tauU = (unsigned)__builtin_amdgcn_readlane((int)(unsigned)(t >> 32), 0);
    drain_u<4>(t, kv.y, 1, tauU);
    drain_u<4>(t, kv.z, 2, tauU);
    drain_u<4>(t, kv.w, 3, tauU);
  }
#pragma unroll 1
  for (int it = 1; it < P_ / 256; ++it) {
    uint4 kv = *(const uint4*)(sp + it * 256 + lane * 4);
    int cb = it * 256;
    drain_u<4>(t, kv.x, cb + 0, tauU);
    drain_u<4>(t, kv.y, cb + 1, tauU);
    drain_u<4>(t, kv.z, cb + 2, tauU);
    drain_u<4>(t, kv.w, cb + 3, tauU);
  }
  if (lane < K_)
    idx[((size_t)b * P_ + row) * K_ + lane] = (int)(~(unsigned)t);
}

// ---------------- Kernel 5: e2 = x1@(W3a-W3b)+b3, bb2 = x1@W3b ----------
__global__ __launch_bounds__(256) void ebb_kernel(
    const float* __restrict__ x1, const float* __restrict__ W3,
    const float* __restrict__ b3, float* __restrict__ e2,
    float* __restrict__ bb2) {
  __shared__ float xs[16 * 64];
  size_t p0 = (size_t)blockIdx.x * 16;
  for (int v = threadIdx.x; v < 16 * 64; v += 256) xs[v] = x1[p0 * 64 + v];
  __syncthreads();
  int n = threadIdx.x & 127;
  int which = threadIdx.x >> 7;  // wave-uniform
  float acc[16];
#pragma unroll
  for (int p = 0; p < 16; ++p) acc[p] = 0.f;
  for (int c = 0; c < 64; ++c) {
    float wa = W3[c * 128 + n];
    float wb = W3[(64 + c) * 128 + n];
    float wv = which ? wb : (wa - wb);
#pragma unroll
    for (int p = 0; p < 16; ++p) acc[p] += xs[p * 64 + c] * wv;
  }
  float bias = which ? 0.f : b3[n];
  float* dst = which ? bb2 : e2;
#pragma unroll
  for (int p = 0; p < 16; ++p) dst[(p0 + p) * 128 + n] = acc[p] + bias;
}

// ---------------- Kernel 6: x2 gather-max + hp@Wl + per-tile max --------
__global__ __launch_bounds__(256) void final_kernel(
    const float* __restrict__ x1, const float* __restrict__ e2,
    const float* __restrict__ bb2, const int* __restrict__ idx,
    const float* __restrict__ Wl, const float* __restrict__ bl,
    float* __restrict__ partial) {
  __shared__ float hp[32][192];
  __shared__ float smax[2][128];
  int b = blockIdx.y;
  int i0 = blockIdx.x * 32;
  size_t gp0 = (size_t)b * P_ + i0;
  for (int v = threadIdx.x; v < 32 * 64; v += 256) {
    int p = v >> 6, c = v & 63;
    hp[p][c] = x1[(gp0 + p) * 64 + c];
  }
  for (int v = threadIdx.x; v < 32 * 128; v += 256) {
    int p = v >> 7, n = v & 127;
    size_t gp = gp0 + p;
    const int* ji = idx + gp * K_;
    float m = -INFINITY;
    for (int k = 0; k < K_; ++k) {
      int j = ji[k];
      m = fmaxf(m, bb2[((size_t)b * P_ + j) * 128 + n]);
    }
    hp[p][64 + n] = e2[gp * 128 + n] + m;
  }
  __syncthreads();
  int n = threadIdx.x & 127;
  int pg = threadIdx.x >> 7;
  float acc[16];
#pragma unroll
  for (int p = 0; p < 16; ++p) acc[p] = 0.f;
  for (int c = 0; c < 192; ++c) {
    float wv = Wl[c * 128 + n];
#pragma unroll
    for (int p = 0; p < 16; ++p) acc[p] += hp[pg * 16 + p][c] * wv;
  }
  float m = -INFINITY;
#pragma unroll
  for (int p = 0; p < 16; ++p) m = fmaxf(m, acc[p]);
  smax[pg][n] = m;
  __syncthreads();
  if (threadIdx.x < 128) {
    float v = fmaxf(smax[0][n], smax[1][n]) + bl[n];
    partial[((size_t)b * 64 + blockIdx.x) * 128 + n] = v;
  }
}

// ---------------- Kernel 7: reduce partial maxes -> out (B,128) ---------
__global__ __launch_bounds__(256) void reduce_kernel(
    const float* __restrict__ partial, float* __restrict__ out) {
  int t = blockIdx.x * 256 + threadIdx.x;  // 4096
  int b = t >> 7, n = t & 127;
  float m = -INFINITY;
  for (int tb = 0; tb < 64; ++tb)
    m = fmaxf(m, partial[((size_t)b * 64 + tb) * 128 + n]);
  out[t] = m;
}

extern "C" void kernel_launch(void* const* d_in, const int* in_sizes, int n_in,
                              void* d_out, int out_size, void* d_ws,
                              size_t ws_size, hipStream_t stream) {
  (void)in_sizes; (void)n_in; (void)out_size;
  const float* pos = (const float*)d_in[0];
  const float* W1  = (const float*)d_in[1];
  const float* b1  = (const float*)d_in[2];
  const float* g1  = (const float*)d_in[3];
  const float* bt1 = (const float*)d_in[4];
  const float* W2  = (const float*)d_in[5];
  const float* b2  = (const float*)d_in[6];
  const float* W3  = (const float*)d_in[7];
  const float* b3  = (const float*)d_in[8];
  const float* Wl  = (const float*)d_in[9];
  const float* bl  = (const float*)d_in[10];
  float* out = (float*)d_out;

  // Workspace layout (bytes), peak 90,439,680:
  //   [0, 5242880)          idx (idx1 then idx2)
  //   [5242880, 22020096)   x1
  //   [22020096, 22282240)  d2
  //   [22282240, 23330816)  partial
  //   [23330816, 90439680)  region: pts4 -> scores -> e2|bb2
  char* w = (char*)d_ws;
  int*      idxp  = (int*)(w + 0);
  float*    x1p   = (float*)(w + 5242880);
  float*    d2p   = (float*)(w + 22020096);
  float*    partp = (float*)(w + 22282240);
  float4*   pts4p = (float4*)(w + 23330816);    // live only during knn3
  unsigned* scp   = (unsigned*)(w + 23330816);  // live only during kNN-2
  float*    e2p   = (float*)(w + 23330816);     // live after kNN-2
  float*    bb2p  = (float*)(w + 23330816 + 33554432);

  // Adaptive score-chunk: per batch 2048*2048*4 = 16,777,216 B.
  size_t avail = ws_size > 23330816 ? ws_size - 23330816 : 0;
  int chunkB = 4;  // guaranteed: region holds 4 x 16 MB
  if (avail >= (size_t)32 * 16777216) chunkB = 32;
  else if (avail >= (size_t)16 * 16777216) chunkB = 16;
  else if (avail >= (size_t)8 * 16777216) chunkB = 8;

  pts4_kernel<<<dim3(B_ * P_ / 256), 256, 0, stream>>>(pos, pts4p);
  knn3_kernel<<<dim3(P_ / 32, B_), 256, 0, stream>>>(pts4p, idxp);
  layer1_kernel<<<dim3(P_ / 4, B_), 256, 0, stream>>>(
      pos, W1, b1, g1, bt1, W2, b2, idxp, x1p, d2p);
  for (int cb = 0; cb < B_; cb += chunkB) {
    gemm_scores_kernel<<<dim3(P_ / 128, P_ / 128, chunkB), 256, 0, stream>>>(
        x1p, d2p, scp, cb);
    knn_select_kernel<<<dim3(P_ / 4, chunkB), 256, 0, stream>>>(
        scp, idxp, cb);
  }
  ebb_kernel<<<dim3(B_ * P_ / 16), 256, 0, stream>>>(x1p, W3, b3, e2p, bb2p);
  final_kernel<<<dim3(P_ / 32, B_), 256, 0, stream>>>(
      x1p, e2p, bb2p, idxp, Wl, bl, partp);
  reduce_kernel<<<dim3(16), 256, 0, stream>>>(partp, out);
}

// Round 14
// 944.335 us; speedup vs baseline: 1.7866x; 1.0532x over previous
//
#include <hip/hip_runtime.h>

#define B_ 32
#define P_ 2048
#define K_ 20

// ---- order-preserving (key, idx) packing -------------------------------
__device__ inline unsigned monok(float key) {
  unsigned u = __float_as_uint(key);
  return u ^ (((unsigned)((int)u >> 31)) | 0x80000000u);  // monotone f32->u32
}
__device__ inline float unmonok(unsigned u) {
  return __uint_as_float((u & 0x80000000u) ? (u ^ 0x80000000u) : ~u);
}
__device__ inline unsigned long long pack_key(float key, int j) {
  return ((unsigned long long)monok(key) << 32) | (unsigned)(~j);
}

// Full ascending bitonic sort of 64 u64 across the wave's lanes.
__device__ inline unsigned long long sort64(unsigned long long v, int lane) {
#pragma unroll
  for (int k = 2; k <= 64; k <<= 1) {
#pragma unroll
    for (int j = k >> 1; j > 0; j >>= 1) {
      unsigned long long o = __shfl_xor(v, j, 64);
      bool keepMin = ((lane & j) == 0) == ((lane & k) == 0);
      unsigned long long mn = v < o ? v : o;
      unsigned long long mx = v < o ? o : v;
      v = keepMin ? mn : mx;
    }
  }
  return v;
}

// Seed top-20 list from 64 candidates: sort asc, top-20 -> lanes 0..19.
__device__ inline unsigned long long topk_seed(unsigned long long x, int lane) {
  unsigned long long s = sort64(x, lane);
  unsigned long long v = __shfl(s, lane + 44, 64);
  return (lane < K_) ? v : ~0ULL;
}

// ---- slim wave-distributed top-K drains --------------------------------
template <int STRIDE>
__device__ inline void drain_f(unsigned long long& t, float keyf, int jbase,
                               unsigned& tauU, float& tauf) {
  unsigned long long mask = __ballot(keyf >= tauf);
  while (mask) {
    int src = (int)__builtin_ctzll(mask);
    mask &= mask - 1;
    unsigned kb = (unsigned)__builtin_amdgcn_readlane(__float_as_int(keyf), src);
    unsigned kU = kb ^ (((unsigned)((int)kb >> 31)) | 0x80000000u);
    if (kU < tauU) continue;  // stale (scalar cmp+branch)
    unsigned long long xi =
        ((unsigned long long)kU << 32) | (unsigned)(~(jbase + src * STRIDE));
    unsigned long long up = __shfl_down(t, 1, 64);
    bool c1 = t < xi;
    bool c2 = up < xi;
    unsigned long long v = c1 ? xi : t;
    t = c2 ? up : v;
    tauU = (unsigned)__builtin_amdgcn_readlane((int)(unsigned)(t >> 32), 0);
    tauf = unmonok(tauU);
  }
}
template <int STRIDE>
__device__ inline void drain_u(unsigned long long& t, unsigned keyU, int jbase,
                               unsigned& tauU) {
  unsigned long long mask = __ballot(keyU >= tauU);
  while (mask) {
    int src = (int)__builtin_ctzll(mask);
    mask &= mask - 1;
    unsigned kU = (unsigned)__builtin_amdgcn_readlane((int)keyU, src);
    if (kU < tauU) continue;
    unsigned long long xi =
        ((unsigned long long)kU << 32) | (unsigned)(~(jbase + src * STRIDE));
    unsigned long long up = __shfl_down(t, 1, 64);
    bool c1 = t < xi;
    bool c2 = up < xi;
    unsigned long long v = c1 ? xi : t;
    t = c2 ? up : v;
    tauU = (unsigned)__builtin_amdgcn_readlane((int)(unsigned)(t >> 32), 0);
  }
}

// ---------------- Kernel 0: pts4[i] = (x, y, z, x^2+y^2+z^2) ------------
__global__ __launch_bounds__(256) void pts4_kernel(
    const float* __restrict__ pos, float4* __restrict__ pts4) {
  int i = blockIdx.x * 256 + threadIdx.x;  // over B*P
  const float* p = pos + (size_t)i * 3;
  float x = p[0], y = p[1], z = p[2];
  pts4[i] = make_float4(x, y, z, x * x + y * y + z * z);
}

// ---------------- Kernel 1: kNN on 3-D positions -> idx1 ----------------
// LDS-free: candidates read straight from global pts4 (L2-resident,
// coalesced 1KB/wave/chunk). Block 256 (4 waves), wave owns 4 rows.
// (4 rows/wave is the measured sweet spot: VGPR 24, occ 73%; 8 rows
// starves registers and regressed — R13.)
__global__ __launch_bounds__(256) void knn3_kernel(
    const float4* __restrict__ pts4, int* __restrict__ idx) {
  int b = blockIdx.y;
  const float4* pb = pts4 + (size_t)b * P_;
  int wv = threadIdx.x >> 6;
  int lane = threadIdx.x & 63;
  int row0 = blockIdx.x * 16 + wv * 4;
  float4 pi[4];
#pragma unroll
  for (int rr = 0; rr < 4; ++rr) {
    float4 p = pb[row0 + rr];  // broadcast load
    pi[rr] = make_float4(2.f * p.x, 2.f * p.y, 2.f * p.z, p.w);
  }
  unsigned long long t[4];
  unsigned tauU[4];
  float tauf[4];
  {
    float4 pj = pb[lane];
#pragma unroll
    for (int rr = 0; rr < 4; ++rr) {
      float key = fmaf(pi[rr].x, pj.x,
                  fmaf(pi[rr].y, pj.y, fmaf(pi[rr].z, pj.z, -pj.w)));
      t[rr] = topk_seed(pack_key(key, lane), lane);
      tauU[rr] = (unsigned)__builtin_amdgcn_readlane(
          (int)(unsigned)(t[rr] >> 32), 0);
      tauf[rr] = unmonok(tauU[rr]);
    }
  }
#pragma unroll 1
  for (int ch = 1; ch < 32; ++ch) {
    float4 pj = pb[ch * 64 + lane];  // coalesced global (L2)
#pragma unroll
    for (int rr = 0; rr < 4; ++rr) {
      float key = fmaf(pi[rr].x, pj.x,
                  fmaf(pi[rr].y, pj.y, fmaf(pi[rr].z, pj.z, -pj.w)));
      drain_f<1>(t[rr], key, ch * 64, tauU[rr], tauf[rr]);
    }
  }
  if (lane < K_) {
#pragma unroll
    for (int rr = 0; rr < 4; ++rr)
      idx[((size_t)b * P_ + row0 + rr) * K_ + lane] = (int)(~(unsigned)t[rr]);
  }
}

// ---------------- Kernel 3: layer-1 edge MLP + max over K -> x1, d2 -----
__global__ __launch_bounds__(256) void layer1_kernel(
    const float* __restrict__ pos, const float* __restrict__ W1,
    const float* __restrict__ b1, const float* __restrict__ g1,
    const float* __restrict__ bt1, const float* __restrict__ W2,
    const float* __restrict__ b2, const int* __restrict__ idx,
    float* __restrict__ x1, float* __restrict__ d2out) {
  __shared__ __align__(16) float W2t[64 * 68];  // W2t[n][c] = W2[c][n]
  __shared__ __align__(16) float A[80 * 68];    // T rows: p*20+k
  __shared__ float pmax[4][4][64];
  int b = blockIdx.y;
  int tid = threadIdx.x;
  int lane = tid & 63;
  int w = tid >> 6;
  for (int t = tid; t < 64 * 64; t += 256) {
    int c = t >> 6, n = t & 63;
    W2t[n * 68 + c] = W2[c * 64 + n];
  }
  int i = blockIdx.x * 4 + w;
  size_t ip = (size_t)b * P_ + i;
  const float* posi = pos + ip * 3;
  float px = posi[0], py = posi[1], pz = posi[2];
  int c = lane;
  float w3 = W1[3 * 64 + c], w4 = W1[4 * 64 + c], w5 = W1[5 * 64 + c];
  float cv = px * (W1[0 * 64 + c] - w3) + py * (W1[1 * 64 + c] - w4) +
             pz * (W1[2 * 64 + c] - w5) + b1[c];
  float g = g1[c], bt = bt1[c];
  const int* ji = idx + ip * K_;
  const float* posb = pos + (size_t)b * P_ * 3;
  for (int k = 0; k < K_; ++k) {
    int j = ji[k];  // broadcast
    const float* pj = posb + (size_t)j * 3;
    float xj = pj[0], yj = pj[1], zj = pj[2];
    float t = cv + fmaf(xj, w3, fmaf(yj, w4, zj * w5));
    t = fmaxf(fmaf(t, g, bt), 0.f);
    A[(w * K_ + k) * 68 + c] = t;
  }
  __syncthreads();

  int tr = tid >> 4;  // rows tr*5..tr*5+4
  int tc = tid & 15;  // cols tc + 16*cc
  float acc[5][4];
#pragma unroll
  for (int a = 0; a < 5; ++a)
#pragma unroll
    for (int cc = 0; cc < 4; ++cc) acc[a][cc] = 0.f;
#pragma unroll
  for (int c4 = 0; c4 < 16; ++c4) {
    float4 af[5], bf[4];
#pragma unroll
    for (int a = 0; a < 5; ++a)
      af[a] = *(const float4*)(&A[(tr * 5 + a) * 68 + c4 * 4]);
#pragma unroll
    for (int cc = 0; cc < 4; ++cc)
      bf[cc] = *(const float4*)(&W2t[(tc + 16 * cc) * 68 + c4 * 4]);
#pragma unroll
    for (int a = 0; a < 5; ++a)
#pragma unroll
      for (int cc = 0; cc < 4; ++cc) {
        float s = acc[a][cc];
        s = fmaf(af[a].x, bf[cc].x, s);
        s = fmaf(af[a].y, bf[cc].y, s);
        s = fmaf(af[a].z, bf[cc].z, s);
        s = fmaf(af[a].w, bf[cc].w, s);
        acc[a][cc] = s;
      }
  }
#pragma unroll
  for (int cc = 0; cc < 4; ++cc) {
    float m = acc[0][cc];
#pragma unroll
    for (int a = 1; a < 5; ++a) m = fmaxf(m, acc[a][cc]);
    pmax[tr >> 2][tr & 3][tc + 16 * cc] = m;
  }
  __syncthreads();
  {
    int p = tid >> 6, col = tid & 63;
    float m = fmaxf(fmaxf(pmax[p][0][col], pmax[p][1][col]),
                    fmaxf(pmax[p][2][col], pmax[p][3][col]));
    m += b2[col];
    size_t ipp = (size_t)b * P_ + blockIdx.x * 4 + p;
    x1[ipp * 64 + col] = m;
    float s = m * m;
#pragma unroll
    for (int off = 32; off; off >>= 1) s += __shfl_xor(s, off, 64);
    if (col == 0) d2out[ipp] = s;
  }
}

// ---------------- Kernel 4a: Gram scores -> packed u32 keys (global) ----
// grid (P/128, P/128, chunkB), block 256. 128x128 tile, K=64 staged once,
// 8x8 microtile.
__global__ __launch_bounds__(256) void gemm_scores_kernel(
    const float* __restrict__ x1, const float* __restrict__ d2g,
    unsigned* __restrict__ scores, int chunkBase) {
  __shared__ __align__(16) float As[128 * 68];   // 34,816 B
  __shared__ __align__(16) float Bs[128 * 68];   // 34,816 B
  __shared__ float d2s[128];
  int bz = blockIdx.z;
  int b = chunkBase + bz;
  int r0 = blockIdx.x * 128;
  int c0 = blockIdx.y * 128;
  const float* xb = x1 + (size_t)b * P_ * 64;
  unsigned* sb = scores + ((size_t)bz * P_ + r0) * P_;
  int tid = threadIdx.x;
  int tr = tid >> 4;  // 0..15 -> rows tr*8+a
  int tc = tid & 15;  // cols tc+16*c

  for (int g = tid; g < 128 * 16; g += 256) {
    int r = g >> 4, c4 = g & 15;
    *(float4*)&As[r * 68 + c4 * 4] =
        *(const float4*)(xb + (size_t)(r0 + r) * 64 + c4 * 4);
  }
  for (int g = tid; g < 128 * 16; g += 256) {
    int r = g >> 4, c4 = g & 15;
    *(float4*)&Bs[r * 68 + c4 * 4] =
        *(const float4*)(xb + (size_t)(c0 + r) * 64 + c4 * 4);
  }
  if (tid < 128) d2s[tid] = d2g[(size_t)b * P_ + c0 + tid];
  __syncthreads();

  float acc[8][8];
#pragma unroll
  for (int a = 0; a < 8; ++a)
#pragma unroll
    for (int c = 0; c < 8; ++c) acc[a][c] = 0.f;
#pragma unroll
  for (int c4 = 0; c4 < 16; ++c4) {
    float4 af[8], bf[8];
#pragma unroll
    for (int a = 0; a < 8; ++a)
      af[a] = *(const float4*)(&As[(tr * 8 + a) * 68 + c4 * 4]);  // broadcast
#pragma unroll
    for (int c = 0; c < 8; ++c)
      bf[c] = *(const float4*)(&Bs[(tc + 16 * c) * 68 + c4 * 4]);  // 2-way
#pragma unroll
    for (int a = 0; a < 8; ++a)
#pragma unroll
      for (int c = 0; c < 8; ++c) {
        float s = acc[a][c];
        s = fmaf(af[a].x, bf[c].x, s);
        s = fmaf(af[a].y, bf[c].y, s);
        s = fmaf(af[a].z, bf[c].z, s);
        s = fmaf(af[a].w, bf[c].w, s);
        acc[a][c] = s;
      }
  }
#pragma unroll
  for (int a = 0; a < 8; ++a)
#pragma unroll
    for (int c = 0; c < 8; ++c) {
      int col = tc + 16 * c;
      sb[(size_t)(tr * 8 + a) * P_ + c0 + col] =
          monok(2.f * acc[a][c] - d2s[col]);
    }
}

// ---------------- Kernel 4b: select top-20 per row from key buffer ------
// grid (P/4, chunkB), block 256: one wave per row, no LDS.
__global__ __launch_bounds__(256) void knn_select_kernel(
    const unsigned* __restrict__ scores, int* __restrict__ idx,
    int chunkBase) {
  int bb = blockIdx.y;
  int b = chunkBase + bb;
  int row = blockIdx.x * 4 + (threadIdx.x >> 6);
  int lane = threadIdx.x & 63;
  const unsigned* sp = scores + ((size_t)bb * P_ + row) * P_;
  unsigned long long t;
  unsigned tauU;
  // it = 0: seed from first stripe (q==0), drain q=1..3
  {
    uint4 kv = *(const uint4*)(sp + lane * 4);
    t = topk_seed(((unsigned long long)kv.x << 32) | (unsigned)(~(lane * 4)),
                  lane);
    tauU = (unsigned)__builtin_amdgcn_readlane((int)(unsigned)(t >> 32), 0);
    drain_u<4>(t, kv.y, 1, tauU);
    drain_u<4>(t, kv.z, 2, tauU);
    drain_u<4>(t, kv.w, 3, tauU);
  }
#pragma unroll 1
  for (int it = 1; it < P_ / 256; ++it) {
    uint4 kv = *(const uint4*)(sp + it * 256 + lane * 4);
    int cb = it * 256;
    drain_u<4>(t, kv.x, cb + 0, tauU);
    drain_u<4>(t, kv.y, cb + 1, tauU);
    drain_u<4>(t, kv.z, cb + 2, tauU);
    drain_u<4>(t, kv.w, cb + 3, tauU);
  }
  if (lane < K_)
    idx[((size_t)b * P_ + row) * K_ + lane] = (int)(~(unsigned)t);
}

// ---------------- Kernel 5: e2 = x1@(W3a-W3b)+b3, bb2 = x1@W3b ----------
__global__ __launch_bounds__(256) void ebb_kernel(
    const float* __restrict__ x1, const float* __restrict__ W3,
    const float* __restrict__ b3, float* __restrict__ e2,
    float* __restrict__ bb2) {
  __shared__ float xs[16 * 64];
  size_t p0 = (size_t)blockIdx.x * 16;
  for (int v = threadIdx.x; v < 16 * 64; v += 256) xs[v] = x1[p0 * 64 + v];
  __syncthreads();
  int n = threadIdx.x & 127;
  int which = threadIdx.x >> 7;  // wave-uniform
  float acc[16];
#pragma unroll
  for (int p = 0; p < 16; ++p) acc[p] = 0.f;
  for (int c = 0; c < 64; ++c) {
    float wa = W3[c * 128 + n];
    float wb = W3[(64 + c) * 128 + n];
    float wv = which ? wb : (wa - wb);
#pragma unroll
    for (int p = 0; p < 16; ++p) acc[p] += xs[p * 64 + c] * wv;
  }
  float bias = which ? 0.f : b3[n];
  float* dst = which ? bb2 : e2;
#pragma unroll
  for (int p = 0; p < 16; ++p) dst[(p0 + p) * 128 + n] = acc[p] + bias;
}

// ---------------- Kernel 6: x2 gather-max + hp@Wl + per-tile max --------
__global__ __launch_bounds__(256) void final_kernel(
    const float* __restrict__ x1, const float* __restrict__ e2,
    const float* __restrict__ bb2, const int* __restrict__ idx,
    const float* __restrict__ Wl, const float* __restrict__ bl,
    float* __restrict__ partial) {
  __shared__ float hp[32][192];
  __shared__ float smax[2][128];
  int b = blockIdx.y;
  int i0 = blockIdx.x * 32;
  size_t gp0 = (size_t)b * P_ + i0;
  for (int v = threadIdx.x; v < 32 * 64; v += 256) {
    int p = v >> 6, c = v & 63;
    hp[p][c] = x1[(gp0 + p) * 64 + c];
  }
  for (int v = threadIdx.x; v < 32 * 128; v += 256) {
    int p = v >> 7, n = v & 127;
    size_t gp = gp0 + p;
    const int* ji = idx + gp * K_;
    float m = -INFINITY;
    for (int k = 0; k < K_; ++k) {
      int j = ji[k];
      m = fmaxf(m, bb2[((size_t)b * P_ + j) * 128 + n]);
    }
    hp[p][64 + n] = e2[gp * 128 + n] + m;
  }
  __syncthreads();
  int n = threadIdx.x & 127;
  int pg = threadIdx.x >> 7;
  float acc[16];
#pragma unroll
  for (int p = 0; p < 16; ++p) acc[p] = 0.f;
  for (int c = 0; c < 192; ++c) {
    float wv = Wl[c * 128 + n];
#pragma unroll
    for (int p = 0; p < 16; ++p) acc[p] += hp[pg * 16 + p][c] * wv;
  }
  float m = -INFINITY;
#pragma unroll
  for (int p = 0; p < 16; ++p) m = fmaxf(m, acc[p]);
  smax[pg][n] = m;
  __syncthreads();
  if (threadIdx.x < 128) {
    float v = fmaxf(smax[0][n], smax[1][n]) + bl[n];
    partial[((size_t)b * 64 + blockIdx.x) * 128 + n] = v;
  }
}

// ---------------- Kernel 7: reduce partial maxes -> out (B,128) ---------
__global__ __launch_bounds__(256) void reduce_kernel(
    const float* __restrict__ partial, float* __restrict__ out) {
  int t = blockIdx.x * 256 + threadIdx.x;  // 4096
  int b = t >> 7, n = t & 127;
  float m = -INFINITY;
  for (int tb = 0; tb < 64; ++tb)
    m = fmaxf(m, partial[((size_t)b * 64 + tb) * 128 + n]);
  out[t] = m;
}

extern "C" void kernel_launch(void* const* d_in, const int* in_sizes, int n_in,
                              void* d_out, int out_size, void* d_ws,
                              size_t ws_size, hipStream_t stream) {
  (void)in_sizes; (void)n_in; (void)out_size;
  const float* pos = (const float*)d_in[0];
  const float* W1  = (const float*)d_in[1];
  const float* b1  = (const float*)d_in[2];
  const float* g1  = (const float*)d_in[3];
  const float* bt1 = (const float*)d_in[4];
  const float* W2  = (const float*)d_in[5];
  const float* b2  = (const float*)d_in[6];
  const float* W3  = (const float*)d_in[7];
  const float* b3  = (const float*)d_in[8];
  const float* Wl  = (const float*)d_in[9];
  const float* bl  = (const float*)d_in[10];
  float* out = (float*)d_out;

  // Workspace layout (bytes), peak 90,439,680:
  //   [0, 5242880)          idx (idx1 then idx2)
  //   [5242880, 22020096)   x1
  //   [22020096, 22282240)  d2
  //   [22282240, 23330816)  partial
  //   [23330816, 90439680)  region: pts4 -> scores -> e2|bb2
  char* w = (char*)d_ws;
  int*      idxp  = (int*)(w + 0);
  float*    x1p   = (float*)(w + 5242880);
  float*    d2p   = (float*)(w + 22020096);
  float*    partp = (float*)(w + 22282240);
  float4*   pts4p = (float4*)(w + 23330816);    // live only during knn3
  unsigned* scp   = (unsigned*)(w + 23330816);  // live only during kNN-2
  float*    e2p   = (float*)(w + 23330816);     // live after kNN-2
  float*    bb2p  = (float*)(w + 23330816 + 33554432);

  // Adaptive score-chunk: per batch 2048*2048*4 = 16,777,216 B.
  size_t avail = ws_size > 23330816 ? ws_size - 23330816 : 0;
  int chunkB = 4;  // guaranteed: region holds 4 x 16 MB
  if (avail >= (size_t)32 * 16777216) chunkB = 32;
  else if (avail >= (size_t)16 * 16777216) chunkB = 16;
  else if (avail >= (size_t)8 * 16777216) chunkB = 8;

  pts4_kernel<<<dim3(B_ * P_ / 256), 256, 0, stream>>>(pos, pts4p);
  knn3_kernel<<<dim3(P_ / 16, B_), 256, 0, stream>>>(pts4p, idxp);
  layer1_kernel<<<dim3(P_ / 4, B_), 256, 0, stream>>>(
      pos, W1, b1, g1, bt1, W2, b2, idxp, x1p, d2p);
  for (int cb = 0; cb < B_; cb += chunkB) {
    gemm_scores_kernel<<<dim3(P_ / 128, P_ / 128, chunkB), 256, 0, stream>>>(
        x1p, d2p, scp, cb);
    knn_select_kernel<<<dim3(P_ / 4, chunkB), 256, 0, stream>>>(
        scp, idxp, cb);
  }
  ebb_kernel<<<dim3(B_ * P_ / 16), 256, 0, stream>>>(x1p, W3, b3, e2p, bb2p);
  final_kernel<<<dim3(P_ / 32, B_), 256, 0, stream>>>(
      x1p, e2p, bb2p, idxp, Wl, bl, partp);
  reduce_kernel<<<dim3(16), 256, 0, stream>>>(partp, out);
}

// Round 15
// 918.779 us; speedup vs baseline: 1.8363x; 1.0278x over previous
//
#include <hip/hip_runtime.h>

#define B_ 32
#define P_ 2048
#define K_ 20

// ---- order-preserving (key, idx) packing -------------------------------
__device__ inline unsigned monok(float key) {
  unsigned u = __float_as_uint(key);
  return u ^ (((unsigned)((int)u >> 31)) | 0x80000000u);  // monotone f32->u32
}
__device__ inline float unmonok(unsigned u) {
  return __uint_as_float((u & 0x80000000u) ? (u ^ 0x80000000u) : ~u);
}
__device__ inline unsigned long long pack_key(float key, int j) {
  return ((unsigned long long)monok(key) << 32) | (unsigned)(~j);
}

// Full ascending bitonic sort of 64 u64 across the wave's lanes.
__device__ inline unsigned long long sort64(unsigned long long v, int lane) {
#pragma unroll
  for (int k = 2; k <= 64; k <<= 1) {
#pragma unroll
    for (int j = k >> 1; j > 0; j >>= 1) {
      unsigned long long o = __shfl_xor(v, j, 64);
      bool keepMin = ((lane & j) == 0) == ((lane & k) == 0);
      unsigned long long mn = v < o ? v : o;
      unsigned long long mx = v < o ? o : v;
      v = keepMin ? mn : mx;
    }
  }
  return v;
}

// Seed top-20 list from 64 candidates: sort asc, top-20 -> lanes 0..19.
__device__ inline unsigned long long topk_seed(unsigned long long x, int lane) {
  unsigned long long s = sort64(x, lane);
  unsigned long long v = __shfl(s, lane + 44, 64);
  return (lane < K_) ? v : ~0ULL;
}

// ---- slim wave-distributed top-K drains (v2) ---------------------------
// Insight: the shfl-shift insert is SELF-GUARDING — inserting a candidate
// below the current 20th-best is a provable no-op (c1/c2 false at every
// lane). So tau needs updating only for the NEXT ballot's filter, not per
// insert: drop the per-insert refresh + stale-skip, refresh once per
// non-empty ballot. Insert body ~29 -> ~18 instr; serial chain shortens
// to shfl -> compare -> select. Output bit-identical.
template <int STRIDE>
__device__ inline void drain_f(unsigned long long& t, float keyf, int jbase,
                               unsigned& tauU, float& tauf) {
  unsigned long long mask = __ballot(keyf >= tauf);
  if (!mask) return;
  do {
    int src = (int)__builtin_ctzll(mask);
    mask &= mask - 1;
    unsigned kb = (unsigned)__builtin_amdgcn_readlane(__float_as_int(keyf), src);
    unsigned kU = kb ^ (((unsigned)((int)kb >> 31)) | 0x80000000u);
    unsigned long long xi =
        ((unsigned long long)kU << 32) | (unsigned)(~(jbase + src * STRIDE));
    unsigned long long up = __shfl_down(t, 1, 64);
    bool c1 = t < xi;
    bool c2 = up < xi;
    unsigned long long v = c1 ? xi : t;
    t = c2 ? up : v;
  } while (mask);
  tauU = (unsigned)__builtin_amdgcn_readlane((int)(unsigned)(t >> 32), 0);
  tauf = unmonok(tauU);
}
template <int STRIDE>
__device__ inline void drain_u(unsigned long long& t, unsigned keyU, int jbase,
                               unsigned& tauU) {
  unsigned long long mask = __ballot(keyU >= tauU);
  if (!mask) return;
  do {
    int src = (int)__builtin_ctzll(mask);
    mask &= mask - 1;
    unsigned kU = (unsigned)__builtin_amdgcn_readlane((int)keyU, src);
    unsigned long long xi =
        ((unsigned long long)kU << 32) | (unsigned)(~(jbase + src * STRIDE));
    unsigned long long up = __shfl_down(t, 1, 64);
    bool c1 = t < xi;
    bool c2 = up < xi;
    unsigned long long v = c1 ? xi : t;
    t = c2 ? up : v;
  } while (mask);
  tauU = (unsigned)__builtin_amdgcn_readlane((int)(unsigned)(t >> 32), 0);
}

// ---------------- Kernel 0: pts4[i] = (x, y, z, x^2+y^2+z^2) ------------
__global__ __launch_bounds__(256) void pts4_kernel(
    const float* __restrict__ pos, float4* __restrict__ pts4) {
  int i = blockIdx.x * 256 + threadIdx.x;  // over B*P
  const float* p = pos + (size_t)i * 3;
  float x = p[0], y = p[1], z = p[2];
  pts4[i] = make_float4(x, y, z, x * x + y * y + z * z);
}

// ---------------- Kernel 1: kNN on 3-D positions -> idx1 ----------------
// LDS-free: candidates read straight from global pts4 (L2-resident,
// coalesced 1KB/wave/chunk). Block 256 (4 waves), wave owns 4 rows.
// (4 rows/wave is the measured sweet spot: VGPR 24, occ 73%; 8 rows
// starves registers and regressed — R13.)
__global__ __launch_bounds__(256) void knn3_kernel(
    const float4* __restrict__ pts4, int* __restrict__ idx) {
  int b = blockIdx.y;
  const float4* pb = pts4 + (size_t)b * P_;
  int wv = threadIdx.x >> 6;
  int lane = threadIdx.x & 63;
  int row0 = blockIdx.x * 16 + wv * 4;
  float4 pi[4];
#pragma unroll
  for (int rr = 0; rr < 4; ++rr) {
    float4 p = pb[row0 + rr];  // broadcast load
    pi[rr] = make_float4(2.f * p.x, 2.f * p.y, 2.f * p.z, p.w);
  }
  unsigned long long t[4];
  unsigned tauU[4];
  float tauf[4];
  {
    float4 pj = pb[lane];
#pragma unroll
    for (int rr = 0; rr < 4; ++rr) {
      float key = fmaf(pi[rr].x, pj.x,
                  fmaf(pi[rr].y, pj.y, fmaf(pi[rr].z, pj.z, -pj.w)));
      t[rr] = topk_seed(pack_key(key, lane), lane);
      tauU[rr] = (unsigned)__builtin_amdgcn_readlane(
          (int)(unsigned)(t[rr] >> 32), 0);
      tauf[rr] = unmonok(tauU[rr]);
    }
  }
#pragma unroll 1
  for (int ch = 1; ch < 32; ++ch) {
    float4 pj = pb[ch * 64 + lane];  // coalesced global (L2)
#pragma unroll
    for (int rr = 0; rr < 4; ++rr) {
      float key = fmaf(pi[rr].x, pj.x,
                  fmaf(pi[rr].y, pj.y, fmaf(pi[rr].z, pj.z, -pj.w)));
      drain_f<1>(t[rr], key, ch * 64, tauU[rr], tauf[rr]);
    }
  }
  if (lane < K_) {
#pragma unroll
    for (int rr = 0; rr < 4; ++rr)
      idx[((size_t)b * P_ + row0 + rr) * K_ + lane] = (int)(~(unsigned)t[rr]);
  }
}

// ---------------- Kernel 3: layer-1 edge MLP + max over K -> x1, d2 -----
__global__ __launch_bounds__(256) void layer1_kernel(
    const float* __restrict__ pos, const float* __restrict__ W1,
    const float* __restrict__ b1, const float* __restrict__ g1,
    const float* __restrict__ bt1, const float* __restrict__ W2,
    const float* __restrict__ b2, const int* __restrict__ idx,
    float* __restrict__ x1, float* __restrict__ d2out) {
  __shared__ __align__(16) float W2t[64 * 68];  // W2t[n][c] = W2[c][n]
  __shared__ __align__(16) float A[80 * 68];    // T rows: p*20+k
  __shared__ float pmax[4][4][64];
  int b = blockIdx.y;
  int tid = threadIdx.x;
  int lane = tid & 63;
  int w = tid >> 6;
  for (int t = tid; t < 64 * 64; t += 256) {
    int c = t >> 6, n = t & 63;
    W2t[n * 68 + c] = W2[c * 64 + n];
  }
  int i = blockIdx.x * 4 + w;
  size_t ip = (size_t)b * P_ + i;
  const float* posi = pos + ip * 3;
  float px = posi[0], py = posi[1], pz = posi[2];
  int c = lane;
  float w3 = W1[3 * 64 + c], w4 = W1[4 * 64 + c], w5 = W1[5 * 64 + c];
  float cv = px * (W1[0 * 64 + c] - w3) + py * (W1[1 * 64 + c] - w4) +
             pz * (W1[2 * 64 + c] - w5) + b1[c];
  float g = g1[c], bt = bt1[c];
  const int* ji = idx + ip * K_;
  const float* posb = pos + (size_t)b * P_ * 3;
  for (int k = 0; k < K_; ++k) {
    int j = ji[k];  // broadcast
    const float* pj = posb + (size_t)j * 3;
    float xj = pj[0], yj = pj[1], zj = pj[2];
    float t = cv + fmaf(xj, w3, fmaf(yj, w4, zj * w5));
    t = fmaxf(fmaf(t, g, bt), 0.f);
    A[(w * K_ + k) * 68 + c] = t;
  }
  __syncthreads();

  int tr = tid >> 4;  // rows tr*5..tr*5+4
  int tc = tid & 15;  // cols tc + 16*cc
  float acc[5][4];
#pragma unroll
  for (int a = 0; a < 5; ++a)
#pragma unroll
    for (int cc = 0; cc < 4; ++cc) acc[a][cc] = 0.f;
#pragma unroll
  for (int c4 = 0; c4 < 16; ++c4) {
    float4 af[5], bf[4];
#pragma unroll
    for (int a = 0; a < 5; ++a)
      af[a] = *(const float4*)(&A[(tr * 5 + a) * 68 + c4 * 4]);
#pragma unroll
    for (int cc = 0; cc < 4; ++cc)
      bf[cc] = *(const float4*)(&W2t[(tc + 16 * cc) * 68 + c4 * 4]);
#pragma unroll
    for (int a = 0; a < 5; ++a)
#pragma unroll
      for (int cc = 0; cc < 4; ++cc) {
        float s = acc[a][cc];
        s = fmaf(af[a].x, bf[cc].x, s);
        s = fmaf(af[a].y, bf[cc].y, s);
        s = fmaf(af[a].z, bf[cc].z, s);
        s = fmaf(af[a].w, bf[cc].w, s);
        acc[a][cc] = s;
      }
  }
#pragma unroll
  for (int cc = 0; cc < 4; ++cc) {
    float m = acc[0][cc];
#pragma unroll
    for (int a = 1; a < 5; ++a) m = fmaxf(m, acc[a][cc]);
    pmax[tr >> 2][tr & 3][tc + 16 * cc] = m;
  }
  __syncthreads();
  {
    int p = tid >> 6, col = tid & 63;
    float m = fmaxf(fmaxf(pmax[p][0][col], pmax[p][1][col]),
                    fmaxf(pmax[p][2][col], pmax[p][3][col]));
    m += b2[col];
    size_t ipp = (size_t)b * P_ + blockIdx.x * 4 + p;
    x1[ipp * 64 + col] = m;
    float s = m * m;
#pragma unroll
    for (int off = 32; off; off >>= 1) s += __shfl_xor(s, off, 64);
    if (col == 0) d2out[ipp] = s;
  }
}

// ---------------- Kernel 4a: Gram scores -> packed u32 keys (global) ----
// grid (P/128, P/128, chunkB), block 256. 128x128 tile, K=64 staged once,
// 8x8 microtile.
__global__ __launch_bounds__(256) void gemm_scores_kernel(
    const float* __restrict__ x1, const float* __restrict__ d2g,
    unsigned* __restrict__ scores, int chunkBase) {
  __shared__ __align__(16) float As[128 * 68];   // 34,816 B
  __shared__ __align__(16) float Bs[128 * 68];   // 34,816 B
  __shared__ float d2s[128];
  int bz = blockIdx.z;
  int b = chunkBase + bz;
  int r0 = blockIdx.x * 128;
  int c0 = blockIdx.y * 128;
  const float* xb = x1 + (size_t)b * P_ * 64;
  unsigned* sb = scores + ((size_t)bz * P_ + r0) * P_;
  int tid = threadIdx.x;
  int tr = tid >> 4;  // 0..15 -> rows tr*8+a
  int tc = tid & 15;  // cols tc+16*c

  for (int g = tid; g < 128 * 16; g += 256) {
    int r = g >> 4, c4 = g & 15;
    *(float4*)&As[r * 68 + c4 * 4] =
        *(const float4*)(xb + (size_t)(r0 + r) * 64 + c4 * 4);
  }
  for (int g = tid; g < 128 * 16; g += 256) {
    int r = g >> 4, c4 = g & 15;
    *(float4*)&Bs[r * 68 + c4 * 4] =
        *(const float4*)(xb + (size_t)(c0 + r) * 64 + c4 * 4);
  }
  if (tid < 128) d2s[tid] = d2g[(size_t)b * P_ + c0 + tid];
  __syncthreads();

  float acc[8][8];
#pragma unroll
  for (int a = 0; a < 8; ++a)
#pragma unroll
    for (int c = 0; c < 8; ++c) acc[a][c] = 0.f;
#pragma unroll
  for (int c4 = 0; c4 < 16; ++c4) {
    float4 af[8], bf[8];
#pragma unroll
    for (int a = 0; a < 8; ++a)
      af[a] = *(const float4*)(&As[(tr * 8 + a) * 68 + c4 * 4]);  // broadcast
#pragma unroll
    for (int c = 0; c < 8; ++c)
      bf[c] = *(const float4*)(&Bs[(tc + 16 * c) * 68 + c4 * 4]);  // 2-way
#pragma unroll
    for (int a = 0; a < 8; ++a)
#pragma unroll
      for (int c = 0; c < 8; ++c) {
        float s = acc[a][c];
        s = fmaf(af[a].x, bf[c].x, s);
        s = fmaf(af[a].y, bf[c].y, s);
        s = fmaf(af[a].z, bf[c].z, s);
        s = fmaf(af[a].w, bf[c].w, s);
        acc[a][c] = s;
      }
  }
#pragma unroll
  for (int a = 0; a < 8; ++a)
#pragma unroll
    for (int c = 0; c < 8; ++c) {
      int col = tc + 16 * c;
      sb[(size_t)(tr * 8 + a) * P_ + c0 + col] =
          monok(2.f * acc[a][c] - d2s[col]);
    }
}

// ---------------- Kernel 4b: select top-20 per row from key buffer ------
// grid (P/4, chunkB), block 256: one wave per row, no LDS.
__global__ __launch_bounds__(256) void knn_select_kernel(
    const unsigned* __restrict__ scores, int* __restrict__ idx,
    int chunkBase) {
  int bb = blockIdx.y;
  int b = chunkBase + bb;
  int row = blockIdx.x * 4 + (threadIdx.x >> 6);
  int lane = threadIdx.x & 63;
  const unsigned* sp = scores + ((size_t)bb * P_ + row) * P_;
  unsigned long long t;
  unsigned tauU;
  // it = 0: seed from first stripe (q==0), drain q=1..3
  {
    uint4 kv = *(const uint4*)(sp + lane * 4);
    t = topk_seed(((unsigned long long)kv.x << 32) | (unsigned)(~(lane * 4)),
                  lane);
    tauU = (unsigned)__builtin_amdgcn_readlane((int)(unsigned)(t >> 32), 0);
    drain_u<4>(t, kv.y, 1, tauU);
    drain_u<4>(t, kv.z, 2, tauU);
    drain_u<4>(t, kv.w, 3, tauU);
  }
#pragma unroll 1
  for (int it = 1; it < P_ / 256; ++it) {
    uint4 kv = *(const uint4*)(sp + it * 256 + lane * 4);
    int cb = it * 256;
    drain_u<4>(t, kv.x, cb + 0, tauU);
    drain_u<4>(t, kv.y, cb + 1, tauU);
    drain_u<4>(t, kv.z, cb + 2, tauU);
    drain_u<4>(t, kv.w, cb + 3, tauU);
  }
  if (lane < K_)
    idx[((size_t)b * P_ + row) * K_ + lane] = (int)(~(unsigned)t);
}

// ---------------- Kernel 5: e2 = x1@(W3a-W3b)+b3, bb2 = x1@W3b ----------
__global__ __launch_bounds__(256) void ebb_kernel(
    const float* __restrict__ x1, const float* __restrict__ W3,
    const float* __restrict__ b3, float* __restrict__ e2,
    float* __restrict__ bb2) {
  __shared__ float xs[16 * 64];
  size_t p0 = (size_t)blockIdx.x * 16;
  for (int v = threadIdx.x; v < 16 * 64; v += 256) xs[v] = x1[p0 * 64 + v];
  __syncthreads();
  int n = threadIdx.x & 127;
  int which = threadIdx.x >> 7;  // wave-uniform
  float acc[16];
#pragma unroll
  for (int p = 0; p < 16; ++p) acc[p] = 0.f;
  for (int c = 0; c < 64; ++c) {
    float wa = W3[c * 128 + n];
    float wb = W3[(64 + c) * 128 + n];
    float wv = which ? wb : (wa - wb);
#pragma unroll
    for (int p = 0; p < 16; ++p) acc[p] += xs[p * 64 + c] * wv;
  }
  float bias = which ? 0.f : b3[n];
  float* dst = which ? bb2 : e2;
#pragma unroll
  for (int p = 0; p < 16; ++p) dst[(p0 + p) * 128 + n] = acc[p] + bias;
}

// ---------------- Kernel 6: x2 gather-max + hp@Wl + per-tile max --------
__global__ __launch_bounds__(256) void final_kernel(
    const float* __restrict__ x1, const float* __restrict__ e2,
    const float* __restrict__ bb2, const int* __restrict__ idx,
    const float* __restrict__ Wl, const float* __restrict__ bl,
    float* __restrict__ partial) {
  __shared__ float hp[32][192];
  __shared__ float smax[2][128];
  int b = blockIdx.y;
  int i0 = blockIdx.x * 32;
  size_t gp0 = (size_t)b * P_ + i0;
  for (int v = threadIdx.x; v < 32 * 64; v += 256) {
    int p = v >> 6, c = v & 63;
    hp[p][c] = x1[(gp0 + p) * 64 + c];
  }
  for (int v = threadIdx.x; v < 32 * 128; v += 256) {
    int p = v >> 7, n = v & 127;
    size_t gp = gp0 + p;
    const int* ji = idx + gp * K_;
    float m = -INFINITY;
    for (int k = 0; k < K_; ++k) {
      int j = ji[k];
      m = fmaxf(m, bb2[((size_t)b * P_ + j) * 128 + n]);
    }
    hp[p][64 + n] = e2[gp * 128 + n] + m;
  }
  __syncthreads();
  int n = threadIdx.x & 127;
  int pg = threadIdx.x >> 7;
  float acc[16];
#pragma unroll
  for (int p = 0; p < 16; ++p) acc[p] = 0.f;
  for (int c = 0; c < 192; ++c) {
    float wv = Wl[c * 128 + n];
#pragma unroll
    for (int p = 0; p < 16; ++p) acc[p] += hp[pg * 16 + p][c] * wv;
  }
  float m = -INFINITY;
#pragma unroll
  for (int p = 0; p < 16; ++p) m = fmaxf(m, acc[p]);
  smax[pg][n] = m;
  __syncthreads();
  if (threadIdx.x < 128) {
    float v = fmaxf(smax[0][n], smax[1][n]) + bl[n];
    partial[((size_t)b * 64 + blockIdx.x) * 128 + n] = v;
  }
}

// ---------------- Kernel 7: reduce partial maxes -> out (B,128) ---------
__global__ __launch_bounds__(256) void reduce_kernel(
    const float* __restrict__ partial, float* __restrict__ out) {
  int t = blockIdx.x * 256 + threadIdx.x;  // 4096
  int b = t >> 7, n = t & 127;
  float m = -INFINITY;
  for (int tb = 0; tb < 64; ++tb)
    m = fmaxf(m, partial[((size_t)b * 64 + tb) * 128 + n]);
  out[t] = m;
}

extern "C" void kernel_launch(void* const* d_in, const int* in_sizes, int n_in,
                              void* d_out, int out_size, void* d_ws,
                              size_t ws_size, hipStream_t stream) {
  (void)in_sizes; (void)n_in; (void)out_size;
  const float* pos = (const float*)d_in[0];
  const float* W1  = (const float*)d_in[1];
  const float* b1  = (const float*)d_in[2];
  const float* g1  = (const float*)d_in[3];
  const float* bt1 = (const float*)d_in[4];
  const float* W2  = (const float*)d_in[5];
  const float* b2  = (const float*)d_in[6];
  const float* W3  = (const float*)d_in[7];
  const float* b3  = (const float*)d_in[8];
  const float* Wl  = (const float*)d_in[9];
  const float* bl  = (const float*)d_in[10];
  float* out = (float*)d_out;

  // Workspace layout (bytes), peak 90,439,680:
  //   [0, 5242880)          idx (idx1 then idx2)
  //   [5242880, 22020096)   x1
  //   [22020096, 22282240)  d2
  //   [22282240, 23330816)  partial
  //   [23330816, 90439680)  region: pts4 -> scores -> e2|bb2
  char* w = (char*)d_ws;
  int*      idxp  = (int*)(w + 0);
  float*    x1p   = (float*)(w + 5242880);
  float*    d2p   = (float*)(w + 22020096);
  float*    partp = (float*)(w + 22282240);
  float4*   pts4p = (float4*)(w + 23330816);    // live only during knn3
  unsigned* scp   = (unsigned*)(w + 23330816);  // live only during kNN-2
  float*    e2p   = (float*)(w + 23330816);     // live after kNN-2
  float*    bb2p  = (float*)(w + 23330816 + 33554432);

  // Adaptive score-chunk: per batch 2048*2048*4 = 16,777,216 B.
  size_t avail = ws_size > 23330816 ? ws_size - 23330816 : 0;
  int chunkB = 4;  // guaranteed: region holds 4 x 16 MB
  if (avail >= (size_t)32 * 16777216) chunkB = 32;
  else if (avail >= (size_t)16 * 16777216) chunkB = 16;
  else if (avail >= (size_t)8 * 16777216) chunkB = 8;

  pts4_kernel<<<dim3(B_ * P_ / 256), 256, 0, stream>>>(pos, pts4p);
  knn3_kernel<<<dim3(P_ / 16, B_), 256, 0, stream>>>(pts4p, idxp);
  layer1_kernel<<<dim3(P_ / 4, B_), 256, 0, stream>>>(
      pos, W1, b1, g1, bt1, W2, b2, idxp, x1p, d2p);
  for (int cb = 0; cb < B_; cb += chunkB) {
    gemm_scores_kernel<<<dim3(P_ / 128, P_ / 128, chunkB), 256, 0, stream>>>(
        x1p, d2p, scp, cb);
    knn_select_kernel<<<dim3(P_ / 4, chunkB), 256, 0, stream>>>(
        scp, idxp, cb);
  }
  ebb_kernel<<<dim3(B_ * P_ / 16), 256, 0, stream>>>(x1p, W3, b3, e2p, bb2p);
  final_kernel<<<dim3(P_ / 32, B_), 256, 0, stream>>>(
      x1p, e2p, bb2p, idxp, Wl, bl, partp);
  reduce_kernel<<<dim3(16), 256, 0, stream>>>(partp, out);
}